// Round 1
// baseline (337.829 us; speedup 1.0000x reference)
//
#include <hip/hip_runtime.h>
#include <hip/hip_bf16.h>
#include <math.h>

#define L_SEQ  2048
#define DMODEL 1024
#define NHEAD  16
#define HEADD  64

typedef __attribute__((ext_vector_type(8))) short short8;
typedef __attribute__((ext_vector_type(4))) short short4v;
typedef __attribute__((ext_vector_type(4))) float f32x4;

#define LDA 32   // unpadded: global_load_lds writes lane*16B contiguous

// RNE float -> bf16 bits
static __device__ __forceinline__ unsigned short f2bf(float f) {
    unsigned int u = __float_as_uint(f);
    unsigned int r = (u + 0x7fffu + ((u >> 16) & 1u)) >> 16;
    return (unsigned short)r;
}

static __device__ __forceinline__ void dma16(const unsigned short* g, unsigned short* l) {
    __builtin_amdgcn_global_load_lds((const __attribute__((address_space(1))) void*)g,
                                     (__attribute__((address_space(3))) void*)l, 16, 0, 0);
}

__global__ void cvt_f32_bf16(const float* __restrict__ in,
                             unsigned short* __restrict__ out, int n4) {
    int i = blockIdx.x * blockDim.x + threadIdx.x;
    if (i >= n4) return;
    float4 v = reinterpret_cast<const float4*>(in)[i];
    ushort4 o;
    o.x = f2bf(v.x); o.y = f2bf(v.y); o.z = f2bf(v.z); o.w = f2bf(v.w);
    reinterpret_cast<ushort4*>(out)[i] = o;
}

// all 4 weights in one dispatch; dst buffers are contiguous (wq|wk|wv|wo)
__global__ void cvt_weights(const float* __restrict__ Wq, const float* __restrict__ Wk,
                            const float* __restrict__ Wv, const float* __restrict__ Wo,
                            unsigned short* __restrict__ dst) {
    int i = blockIdx.x * blockDim.x + threadIdx.x;   // 0..1048575 float4-groups
    int which = i >> 18;                              // 262144 groups per weight
    const float* src = which == 0 ? Wq : which == 1 ? Wk : which == 2 ? Wv : Wo;
    float4 v = reinterpret_cast<const float4*>(src)[i & 262143];
    ushort4 o;
    o.x = f2bf(v.x); o.y = f2bf(v.y); o.z = f2bf(v.z); o.w = f2bf(v.w);
    reinterpret_cast<ushort4*>(dst)[i] = o;
}

// RoPE table: tab[lpos*32+i2] = (cos, sin) of lpos * 10000^(-i2/32).
__global__ void build_rope(float* __restrict__ tab) {
    int i = blockIdx.x * blockDim.x + threadIdx.x;   // 0..65535
    int lpos = i >> 5, i2 = i & 31;
    float inv_f = expf(-0.28782313662425574f * (float)i2);  // 10000^(-i2/32)
    float ang = (float)lpos * inv_f;
    tab[2 * i]     = cosf(ang);
    tab[2 * i + 1] = sinf(ang);
}

// ---------------- fused QKV projection, 256x192 tile, 4-slot ring, counted vmcnt
// M=8192, fused N=3072 (wq|wk|wv contiguous), K=1024, BK=32.
// 8 waves (2M x 4N), per-wave 128x48 output = acc[8][3].
// LDS: A ring 4x16KB + B ring 4x12KB = 112KB. Staging 3 tiles ahead.
// T2 swizzle: element(row,colB) stored at colB ^ (((row>>1)&3)<<4); gload_lds dest
// stays linear, the involution is applied to the GLOBAL source col (rule 21).
#define BKP 32

__global__ __launch_bounds__(512, 2) void proj_qkv(
    const unsigned short* __restrict__ X,
    const unsigned short* __restrict__ Wqkv,
    const float* __restrict__ bq_,
    const float* __restrict__ bk_,
    const float* __restrict__ bv_,
    const float* __restrict__ rope,
    unsigned short* __restrict__ Qb,
    unsigned short* __restrict__ Kb,
    unsigned short* __restrict__ Vr)
{
    __shared__ unsigned short a_lds[4][256 * BKP];   // 4 x 16KB
    __shared__ unsigned short b_lds[4][192 * BKP];   // 4 x 12KB

    const int tid  = threadIdx.x;
    const int lane = tid & 63;
    const int w    = tid >> 6;          // 0..7
    const int wm   = w & 1, wn = w >> 1;
    const int quad = lane >> 4, l16 = lane & 15;

    // bijective XCD swizzle: nwg = 512, 512 % 8 == 0
    const int orig = blockIdx.y * 16 + blockIdx.x;
    const int swz  = (orig & 7) * 64 + (orig >> 3);
    const int bx   = swz & 15;          // n-block 0..15
    const int by   = swz >> 4;          // m-block 0..31
    const int m0   = by * 256;
    const int n0   = bx * 192;

    // staging geometry: lane covers LDS-linear (row = chunk + lane>>2, 16B-slot lane&3);
    // source col pre-swizzled by the involution
    const int st_row = lane >> 2;                                   // 0..15
    const int st_col = (((lane & 3) ^ ((lane >> 3) & 3)) << 3);     // shorts
    // read-side swizzled K-offset (shorts)
    const int rd = ((quad ^ ((l16 >> 1) & 3)) << 3);

    f32x4 acc[8][3];
#pragma unroll
    for (int i = 0; i < 8; ++i)
#pragma unroll
        for (int j = 0; j < 3; ++j) acc[i][j] = (f32x4){0.f, 0.f, 0.f, 0.f};

    const unsigned short* Xs = X    + (size_t)(m0 + w * 32 + st_row) * DMODEL + st_col;
    const unsigned short* Wa = Wqkv + (size_t)(n0 + w * 32 + st_row) * DMODEL + st_col;            // waves 0..3
    const unsigned short* Wb = Wqkv + (size_t)(n0 + 128 + (w - 4) * 16 + st_row) * DMODEL + st_col; // waves 4..7
    const int aBase0 = (w * 32) * BKP, aBase1 = (w * 32 + 16) * BKP;
    const int bBaseL0 = (w * 32) * BKP, bBaseL1 = (w * 32 + 16) * BKP;
    const int bBaseH  = (128 + (w - 4) * 16) * BKP;

    // ---- prologue: stage tiles 0,1,2 into slots 0,1,2
#pragma unroll
    for (int p = 0; p < 3; ++p) {
        const int kk = p * BKP;
        dma16(Xs + kk,               &a_lds[p][aBase0]);
        dma16(Xs + 16 * DMODEL + kk, &a_lds[p][aBase1]);
        if (w < 4) {
            dma16(Wa + kk,               &b_lds[p][bBaseL0]);
            dma16(Wa + 16 * DMODEL + kk, &b_lds[p][bBaseL1]);
        } else {
            dma16(Wb + kk, &b_lds[p][bBaseH]);
        }
    }
    asm volatile("s_waitcnt vmcnt(6)" ::: "memory");   // tile 0 fully landed
    __builtin_amdgcn_s_barrier();

    for (int kt = 0; kt < 32; ++kt) {
        const int slot = kt & 3;
        const int ps   = (kt + 3) & 3;       // == (kt-1)&3 : slot freed last tile
        const int kk   = ((kt + 3) & 31) * BKP;  // wrap keeps vmcnt ledger uniform

        short8 af[4], bf[3];
        // ---------------- phase A (mh = 0): read A-half0 + all B, stage A(kt+3)
#pragma unroll
        for (int i = 0; i < 4; ++i)
            af[i] = *reinterpret_cast<const short8*>(
                &a_lds[slot][(wm * 128 + i * 16 + l16) * BKP + rd]);
#pragma unroll
        for (int j = 0; j < 3; ++j)
            bf[j] = *reinterpret_cast<const short8*>(
                &b_lds[slot][(wn * 48 + j * 16 + l16) * BKP + rd]);
        dma16(Xs + kk,               &a_lds[ps][aBase0]);
        dma16(Xs + 16 * DMODEL + kk, &a_lds[ps][aBase1]);
        __builtin_amdgcn_s_barrier();
        asm volatile("s_waitcnt lgkmcnt(0)" ::: "memory");
        __builtin_amdgcn_sched_barrier(0);
        __builtin_amdgcn_s_setprio(1);
#pragma unroll
        for (int i = 0; i < 4; ++i)
#pragma unroll
            for (int j = 0; j < 3; ++j)
                acc[i][j] = __builtin_amdgcn_mfma_f32_16x16x32_bf16(af[i], bf[j], acc[i][j], 0, 0, 0);
        __builtin_amdgcn_s_setprio(0);
        __builtin_amdgcn_s_barrier();

        // ---------------- phase B (mh = 1): read A-half1 (reuse bf), stage B(kt+3)
#pragma unroll
        for (int i = 0; i < 4; ++i)
            af[i] = *reinterpret_cast<const short8*>(
                &a_lds[slot][(wm * 128 + 64 + i * 16 + l16) * BKP + rd]);
        if (w < 4) {
            dma16(Wa + kk,               &b_lds[ps][bBaseL0]);
            dma16(Wa + 16 * DMODEL + kk, &b_lds[ps][bBaseL1]);
        } else {
            dma16(Wb + kk, &b_lds[ps][bBaseH]);
        }
        __builtin_amdgcn_s_barrier();
        asm volatile("s_waitcnt lgkmcnt(0)" ::: "memory");
        __builtin_amdgcn_sched_barrier(0);
        __builtin_amdgcn_s_setprio(1);
#pragma unroll
        for (int i = 0; i < 4; ++i)
#pragma unroll
            for (int j = 0; j < 3; ++j)
                acc[4 + i][j] = __builtin_amdgcn_mfma_f32_16x16x32_bf16(af[i], bf[j], acc[4 + i][j], 0, 0, 0);
        __builtin_amdgcn_s_setprio(0);
        // tile boundary: outstanding = stages of tiles kt+2,kt+3 (<=6/wave);
        // vmcnt(6) => tile kt+1 fully in LDS. Never drain to 0 in the loop.
        asm volatile("s_waitcnt vmcnt(6)" ::: "memory");
        __builtin_amdgcn_s_barrier();
    }
    asm volatile("s_waitcnt vmcnt(0)" ::: "memory");   // retire wrapped dummy stages

    // ---- epilogue: bias (+ RoPE via table for Q/K); dense [bh][l][d] store
#pragma unroll
    for (int jf = 0; jf < 3; ++jf) {
        int n_g = n0 + wn * 48 + jf * 16 + l16;        // 0..3071, sel-uniform per 16
        int sel = n_g >> 10;
        int nn  = n_g & 1023;
        const float* bias   = sel == 0 ? bq_ : (sel == 1 ? bk_ : bv_);
        unsigned short* out = sel == 0 ? Qb  : (sel == 1 ? Kb  : Vr);
        float bval = bias[nn];
        int d = nn & (HEADD - 1);
        int h = nn >> 6;
        float sgn = (d & 1) ? 1.0f : -1.0f;
        int i2 = d >> 1;
#pragma unroll
        for (int mf = 0; mf < 8; ++mf) {
#pragma unroll
            for (int r = 0; r < 4; ++r) {
                int m_g = m0 + wm * 128 + mf * 16 + quad * 4 + r;
                float v = acc[mf][jf][r] + bval;
                int b    = m_g >> 11;
                int lpos = m_g & (L_SEQ - 1);
                if (sel < 2) {
                    float p = __shfl_xor(v, 1);   // partner (d^1), same row
                    float2 cs = *reinterpret_cast<const float2*>(&rope[(size_t)(lpos * 32 + i2) * 2]);
                    v = v * cs.x + sgn * cs.y * p;
                    if (sel == 0) v *= 0.18033688011112042f;  // log2e/8
                }
                out[((size_t)(b * NHEAD + h) * L_SEQ + lpos) * HEADD + d] = f2bf(v);
            }
        }
    }
}

// ---------------- V transpose: [bh][l][d] -> [bh][d][l] ---------------------
__global__ __launch_bounds__(256) void transpose_v(
    const unsigned short* __restrict__ Vr, unsigned short* __restrict__ Vt)
{
    __shared__ unsigned short tile[64 * 72];
    const int tid = threadIdx.x;
    const int bh  = blockIdx.y;
    const int l0  = blockIdx.x * 64;
#pragma unroll
    for (int t = 0; t < 2; ++t) {
        int c = tid + t * 256;
        int row = c >> 3, cc = (c & 7) << 3;
        int4 v = *reinterpret_cast<const int4*>(Vr + ((size_t)bh * L_SEQ + l0 + row) * HEADD + cc);
        *reinterpret_cast<int4*>(&tile[row * 72 + cc]) = v;
    }
    __syncthreads();
#pragma unroll
    for (int t = 0; t < 2; ++t) {
        int c = tid + t * 256;
        int d = c >> 3, lc = (c & 7) << 3;
        union { unsigned short u[8]; int4 v; } tt;
#pragma unroll
        for (int j = 0; j < 8; ++j) tt.u[j] = tile[(lc + j) * 72 + d];
        *reinterpret_cast<int4*>(Vt + ((size_t)bh * HEADD + d) * L_SEQ + l0 + lc) = tt.v;
    }
}

// ---------------- flash attention (causal), S^T formulation -----------------
#define LDK 88

__global__ __launch_bounds__(256) void attn_fwd(
    const unsigned short* __restrict__ Q,
    const unsigned short* __restrict__ K,
    const unsigned short* __restrict__ Vt,
    unsigned short* __restrict__ Oa)
{
    __shared__ unsigned short k_lds[64 * LDK];
    __shared__ unsigned short v_lds[64 * LDK];
    const int tid  = threadIdx.x;
    const int lane = tid & 63;
    const int w    = tid >> 6;
    const int quad = lane >> 4, l16 = lane & 15;
    const int pair = blockIdx.x;
    const int bh   = blockIdx.y;
    const size_t base = (size_t)bh * L_SEQ * HEADD;

    const int srow0 = tid >> 3;
    const int scc   = (tid & 7) << 3;
    const int b = bh >> 4, h = bh & 15;

    for (int half = 0; half < 2; ++half) {
        const int qb = half ? (31 - pair) : pair;
        const int qrow = qb * 64 + w * 16 + l16;

        short8 qf[2];
#pragma unroll
        for (int ks = 0; ks < 2; ++ks)
            qf[ks] = *reinterpret_cast<const short8*>(Q + base + (size_t)qrow * HEADD + ks * 32 + quad * 8);

        f32x4 o[4];
#pragma unroll
        for (int nt = 0; nt < 4; ++nt) o[nt] = (f32x4){0.f, 0.f, 0.f, 0.f};
        float lsum = 0.f;

        int4 ka0 = *reinterpret_cast<const int4*>(K  + base + (size_t)srow0 * HEADD + scc);
        int4 ka1 = *reinterpret_cast<const int4*>(K  + base + (size_t)(srow0 + 32) * HEADD + scc);
        int4 va0 = *reinterpret_cast<const int4*>(Vt + base + (size_t)srow0 * L_SEQ + scc);
        int4 va1 = *reinterpret_cast<const int4*>(Vt + base + (size_t)(srow0 + 32) * L_SEQ + scc);

        for (int kb = 0; kb <= qb; ++kb) {
            __syncthreads();
            *reinterpret_cast<int4*>(&k_lds[srow0 * LDK + scc])        = ka0;
            *reinterpret_cast<int4*>(&k_lds[(srow0 + 32) * LDK + scc]) = ka1;
            *reinterpret_cast<int4*>(&v_lds[srow0 * LDK + scc])        = va0;
            *reinterpret_cast<int4*>(&v_lds[(srow0 + 32) * LDK + scc]) = va1;
            __syncthreads();

            if (kb < qb) {
                int kn = kb + 1;
                ka0 = *reinterpret_cast<const int4*>(K  + base + (size_t)(kn * 64 + srow0) * HEADD + scc);
                ka1 = *reinterpret_cast<const int4*>(K  + base + (size_t)(kn * 64 + srow0 + 32) * HEADD + scc);
                va0 = *reinterpret_cast<const int4*>(Vt + base + (size_t)srow0 * L_SEQ + kn * 64 + scc);
                va1 = *reinterpret_cast<const int4*>(Vt + base + (size_t)(srow0 + 32) * L_SEQ + kn * 64 + scc);
            }

            f32x4 st[4];
#pragma unroll
            for (int nt = 0; nt < 4; ++nt) st[nt] = (f32x4){0.f, 0.f, 0.f, 0.f};
#pragma unroll
            for (int ks = 0; ks < 2; ++ks)
#pragma unroll
                for (int nt = 0; nt < 4; ++nt) {
                    short8 kf = *reinterpret_cast<const short8*>(&k_lds[(nt * 16 + l16) * LDK + ks * 32 + quad * 8]);
                    st[nt] = __builtin_amdgcn_mfma_f32_16x16x32_bf16(kf, qf[ks], st[nt], 0, 0, 0);
                }

            if (kb == qb) {
#pragma unroll
                for (int nt = 0; nt < 4; ++nt)
#pragma unroll
                    for (int r = 0; r < 4; ++r) {
                        int seqcol = kb * 64 + nt * 16 + quad * 4 + r;
                        if (seqcol > qrow) st[nt][r] = -INFINITY;
                    }
            }

            short4v pfrag[4];
#pragma unroll
            for (int nt = 0; nt < 4; ++nt) {
                float p0 = __builtin_amdgcn_exp2f(st[nt][0]);
                float p1 = __builtin_amdgcn_exp2f(st[nt][1]);
                float p2 = __builtin_amdgcn_exp2f(st[nt][2]);
                float p3 = __builtin_amdgcn_exp2f(st[nt][3]);
                lsum += (p0 + p1) + (p2 + p3);
                unsigned u0 = __float_as_uint(p0) + 0x8000u;
                unsigned u1 = __float_as_uint(p1) + 0x8000u;
                unsigned u2 = __float_as_uint(p2) + 0x8000u;
                unsigned u3 = __float_as_uint(p3) + 0x8000u;
                union { unsigned u[2]; short4v v; } pk;
                pk.u[0] = (u0 >> 16) | (u1 & 0xffff0000u);
                pk.u[1] = (u2 >> 16) | (u3 & 0xffff0000u);
                pfrag[nt] = pk.v;
            }

#pragma unroll
            for (int c = 0; c < 4; ++c)
#pragma unroll
                for (int nt2 = 0; nt2 < 4; ++nt2) {
                    short4v vf = *reinterpret_cast<const short4v*>(
                        &v_lds[(nt2 * 16 + l16) * LDK + c * 16 + quad * 4]);
                    o[nt2] = __builtin_amdgcn_mfma_f32_16x16x16bf16_1k(pfrag[c], vf, o[nt2], 0, 0, 0);
                }
        }

        lsum += __shfl_xor(lsum, 16);
        lsum += __shfl_xor(lsum, 32);
        float rs[4];
#pragma unroll
        for (int r = 0; r < 4; ++r) rs[r] = __shfl(lsum, quad * 4 + r);
#pragma unroll
        for (int r = 0; r < 4; ++r) {
            float inv = 1.0f / rs[r];
            int lg = qb * 64 + w * 16 + quad * 4 + r;
#pragma unroll
            for (int nt = 0; nt < 4; ++nt) {
                int d = nt * 16 + l16;
                Oa[(size_t)(b * L_SEQ + lg) * DMODEL + h * HEADD + d] = f2bf(o[nt][r] * inv);
            }
        }
    }
}

// ---------------- output projection: fp32 out = A @ Wo^T + bo ---------------
__global__ __launch_bounds__(256) void out_gemm(
    const unsigned short* __restrict__ X,
    const unsigned short* __restrict__ W,
    const float* __restrict__ bias,
    float* __restrict__ out)
{
    __shared__ unsigned short a_lds[2][128 * LDA];
    __shared__ unsigned short b_lds[2][128 * LDA];
    const int tid  = threadIdx.x;
    const int lane = tid & 63;
    const int w    = tid >> 6;
    const int wm   = w & 1, wn = w >> 1;
    const int quad = lane >> 4, l16 = lane & 15;
    const int m0 = blockIdx.y * 128;
    const int n0 = blockIdx.x * 128;

    f32x4 acc[4][4];
#pragma unroll
    for (int i = 0; i < 4; ++i)
#pragma unroll
        for (int j = 0; j < 4; ++j) acc[i][j] = (f32x4){0.f, 0.f, 0.f, 0.f};

    const int drow = lane >> 2;
    const int dcol = (lane & 3) << 3;

#pragma unroll
    for (int t = 0; t < 2; ++t) {
        int r0 = w * 32 + t * 16;
        dma16(X + (size_t)(m0 + r0 + drow) * DMODEL + dcol, &a_lds[0][r0 * LDA]);
        dma16(W + (size_t)(n0 + r0 + drow) * DMODEL + dcol, &b_lds[0][r0 * LDA]);
    }

    for (int it = 0; it < 32; ++it) {
        __syncthreads();
        int cb = it & 1;
        if (it < 31) {
            int kk = (it + 1) * 32;
#pragma unroll
            for (int t = 0; t < 2; ++t) {
                int r0 = w * 32 + t * 16;
                dma16(X + (size_t)(m0 + r0 + drow) * DMODEL + kk + dcol, &a_lds[cb ^ 1][r0 * LDA]);
                dma16(W + (size_t)(n0 + r0 + drow) * DMODEL + kk + dcol, &b_lds[cb ^ 1][r0 * LDA]);
            }
        }
        short8 af[4], bf[4];
#pragma unroll
        for (int mt = 0; mt < 4; ++mt)
            af[mt] = *reinterpret_cast<const short8*>(&a_lds[cb][(wm * 64 + mt * 16 + l16) * LDA + quad * 8]);
#pragma unroll
        for (int nt = 0; nt < 4; ++nt)
            bf[nt] = *reinterpret_cast<const short8*>(&b_lds[cb][(wn * 64 + nt * 16 + l16) * LDA + quad * 8]);
#pragma unroll
        for (int mt = 0; mt < 4; ++mt)
#pragma unroll
            for (int nt = 0; nt < 4; ++nt)
                acc[mt][nt] = __builtin_amdgcn_mfma_f32_16x16x32_bf16(af[mt], bf[nt], acc[mt][nt], 0, 0, 0);
    }

#pragma unroll
    for (int nt = 0; nt < 4; ++nt) {
        int n_g = n0 + wn * 64 + nt * 16 + l16;
        float bv = bias[n_g];
#pragma unroll
        for (int mt = 0; mt < 4; ++mt)
#pragma unroll
            for (int r = 0; r < 4; ++r) {
                int m_g = m0 + wm * 64 + mt * 16 + quad * 4 + r;
                out[(size_t)m_g * DMODEL + n_g] = acc[mt][nt][r] + bv;
            }
    }
}

extern "C" void kernel_launch(void* const* d_in, const int* in_sizes, int n_in,
                              void* d_out, int out_size, void* d_ws, size_t ws_size,
                              hipStream_t stream) {
    const float* query = (const float*)d_in[0];
    const float* Wq = (const float*)d_in[1];
    const float* bq = (const float*)d_in[2];
    const float* Wk = (const float*)d_in[3];
    const float* bk = (const float*)d_in[4];
    const float* Wv = (const float*)d_in[5];
    const float* bv = (const float*)d_in[6];
    const float* Wo = (const float*)d_in[7];
    const float* bo = (const float*)d_in[8];
    float* out = (float*)d_out;

    unsigned short* ws  = (unsigned short*)d_ws;
    unsigned short* xb  = ws;                       // 8192*1024
    unsigned short* wqb = xb  + (size_t)8388608;    // 1024*1024 each, CONTIGUOUS wq|wk|wv|wo
    unsigned short* wkb = wqb + 1048576;
    unsigned short* wvb = wkb + 1048576;
    unsigned short* wob = wvb + 1048576;
    unsigned short* Qb  = wob + 1048576;            // [bh][l][d]
    unsigned short* Kb  = Qb  + 8388608;
    unsigned short* Vr  = Kb  + 8388608;            // [bh][l][d]
    unsigned short* Vtb = Vr  + 8388608;            // [bh][d][l]
    unsigned short* Ab  = Vtb + 8388608;            // [b][l][h*d]
    float* rope = (float*)(Ab + 8388608);           // 2048*32 float2 = 512 KB

    (void)wkb; (void)wvb;

    build_rope<<<256, 256, 0, stream>>>(rope);
    cvt_f32_bf16<<<8192, 256, 0, stream>>>(query, xb, 2097152);
    cvt_weights<<<4096, 256, 0, stream>>>(Wq, Wk, Wv, Wo, wqb);

    // fused QKV GEMM: M=8192 x N=3072, 256x192 tiles -> grid (16, 32) = 512 blocks
    proj_qkv<<<dim3(16, 32), 512, 0, stream>>>(xb, wqb, bq, bk, bv, rope, Qb, Kb, Vr);
    transpose_v<<<dim3(32, 64), 256, 0, stream>>>(Vr, Vtb);
    attn_fwd<<<dim3(16, 64), 256, 0, stream>>>(Qb, Kb, Vtb, Ab);
    out_gemm<<<dim3(8, 64), 256, 0, stream>>>(Ab, wob, bo, out);
}

// Round 2
// 325.996 us; speedup vs baseline: 1.0363x; 1.0363x over previous
//
#include <hip/hip_runtime.h>
#include <hip/hip_bf16.h>
#include <math.h>

#define L_SEQ  2048
#define DMODEL 1024
#define NHEAD  16
#define HEADD  64

typedef __attribute__((ext_vector_type(8))) short short8;
typedef __attribute__((ext_vector_type(4))) short short4v;
typedef __attribute__((ext_vector_type(4))) float f32x4;

#define LDA 32   // unpadded: global_load_lds writes lane*16B contiguous

// RNE float -> bf16 bits
static __device__ __forceinline__ unsigned short f2bf(float f) {
    unsigned int u = __float_as_uint(f);
    unsigned int r = (u + 0x7fffu + ((u >> 16) & 1u)) >> 16;
    return (unsigned short)r;
}

static __device__ __forceinline__ void dma16(const unsigned short* g, unsigned short* l) {
    __builtin_amdgcn_global_load_lds((const __attribute__((address_space(1))) void*)g,
                                     (__attribute__((address_space(3))) void*)l, 16, 0, 0);
}

__global__ void cvt_f32_bf16(const float* __restrict__ in,
                             unsigned short* __restrict__ out, int n4) {
    int i = blockIdx.x * blockDim.x + threadIdx.x;
    if (i >= n4) return;
    float4 v = reinterpret_cast<const float4*>(in)[i];
    ushort4 o;
    o.x = f2bf(v.x); o.y = f2bf(v.y); o.z = f2bf(v.z); o.w = f2bf(v.w);
    reinterpret_cast<ushort4*>(out)[i] = o;
}

// all 4 weights in one dispatch; dst buffers are contiguous (wq|wk|wv|wo)
__global__ void cvt_weights(const float* __restrict__ Wq, const float* __restrict__ Wk,
                            const float* __restrict__ Wv, const float* __restrict__ Wo,
                            unsigned short* __restrict__ dst) {
    int i = blockIdx.x * blockDim.x + threadIdx.x;   // 0..1048575 float4-groups
    int which = i >> 18;                              // 262144 groups per weight
    const float* src = which == 0 ? Wq : which == 1 ? Wk : which == 2 ? Wv : Wo;
    float4 v = reinterpret_cast<const float4*>(src)[i & 262143];
    ushort4 o;
    o.x = f2bf(v.x); o.y = f2bf(v.y); o.z = f2bf(v.z); o.w = f2bf(v.w);
    reinterpret_cast<ushort4*>(dst)[i] = o;
}

// RoPE table: tab[lpos*32+i2] = (cos, sin) of lpos * 10000^(-i2/32).
__global__ void build_rope(float* __restrict__ tab) {
    int i = blockIdx.x * blockDim.x + threadIdx.x;   // 0..65535
    int lpos = i >> 5, i2 = i & 31;
    float inv_f = expf(-0.28782313662425574f * (float)i2);  // 10000^(-i2/32)
    float ang = (float)lpos * inv_f;
    tab[2 * i]     = cosf(ang);
    tab[2 * i + 1] = sinf(ang);
}

// ---------------- fused QKV projection -------------------------------------
// 128x128 tile, BK=32, 4 waves (2Mx2N), ring-3 LDS (48 KB -> 3 blocks/CU).
// Counted vmcnt(4) at tile boundaries only (ring depth 2); raw barriers;
// T2 swizzle proven conflict-free in round 1 (6.3M -> 0); setprio on MFMA.
// Grid (24,64): after XCD chunk-swizzle, bx>>3 selects {Q,K,V}.
#define BKP 32

__global__ __launch_bounds__(256) void proj_qkv(
    const unsigned short* __restrict__ X,
    const unsigned short* __restrict__ Wqkv,
    const float* __restrict__ bq_,
    const float* __restrict__ bk_,
    const float* __restrict__ bv_,
    const float* __restrict__ rope,
    unsigned short* __restrict__ Qb,
    unsigned short* __restrict__ Kb,
    unsigned short* __restrict__ Vr)
{
    __shared__ unsigned short a_lds[3][128 * BKP];   // 3 x 8KB
    __shared__ unsigned short b_lds[3][128 * BKP];   // 3 x 8KB

    const int tid  = threadIdx.x;
    const int lane = tid & 63;
    const int w    = tid >> 6;          // 0..3
    const int wm   = w & 1, wn = w >> 1;
    const int quad = lane >> 4, l16 = lane & 15;

    // bijective chunked XCD swizzle: nwg = 1536, 1536 % 8 == 0, chunk = 192
    const int orig = blockIdx.y * 24 + blockIdx.x;
    const int swz  = (orig & 7) * 192 + (orig >> 3);
    const int bx   = swz % 24;          // n-block 0..23 (sel = bx>>3)
    const int by   = swz / 24;          // m-block 0..63
    const int m0   = by * 128;
    const int n0   = bx * 128;

    const int sel = bx >> 3;            // wave-uniform: 0=Q 1=K 2=V
    const float* bias   = sel == 0 ? bq_ : (sel == 1 ? bk_ : bv_);
    unsigned short* out = sel == 0 ? Qb  : (sel == 1 ? Kb  : Vr);

    // staging geometry: LDS-linear dest (row = lane>>2, 16B-slot lane&3);
    // global source col carries the involution (slot ^= (row>>1)&3)
    const int st_row = lane >> 2;                                   // 0..15
    const int st_col = (((lane & 3) ^ ((lane >> 3) & 3)) << 3);     // shorts
    // read-side swizzled K-offset (shorts): slot quad ^ ((row>>1)&3), row%16==l16
    const int rd = ((quad ^ ((l16 >> 1) & 3)) << 3);

    f32x4 acc[4][4];
#pragma unroll
    for (int i = 0; i < 4; ++i)
#pragma unroll
        for (int j = 0; j < 4; ++j) acc[i][j] = (f32x4){0.f, 0.f, 0.f, 0.f};

    const unsigned short* Xs = X    + (size_t)(m0 + w * 32 + st_row) * DMODEL + st_col;
    const unsigned short* Ws = Wqkv + (size_t)(n0 + w * 32 + st_row) * DMODEL + st_col;
    const int ldsA0 = (w * 32) * BKP, ldsA1 = (w * 32 + 16) * BKP;

    // ---- prologue: stage tiles 0,1 into slots 0,1 (4 loads/wave each)
#pragma unroll
    for (int p = 0; p < 2; ++p) {
        const int kk = p * BKP;
        dma16(Xs + kk,               &a_lds[p][ldsA0]);
        dma16(Xs + 16 * DMODEL + kk, &a_lds[p][ldsA1]);
        dma16(Ws + kk,               &b_lds[p][ldsA0]);
        dma16(Ws + 16 * DMODEL + kk, &b_lds[p][ldsA1]);
    }
    asm volatile("s_waitcnt vmcnt(4)" ::: "memory");   // tile 0 fully landed
    __builtin_amdgcn_s_barrier();

    for (int kt = 0; kt < 32; ++kt) {
        const int slot = kt % 3;
        const int ps   = (kt + 2) % 3;           // freed at end of iter kt-1
        const int kk   = ((kt + 2) & 31) * BKP;  // wrap keeps vmcnt ledger uniform

        short8 af[4], bf[2];
        // -------- phase A: read af[0..3] + bf[0..1], stage A(kt+2)
#pragma unroll
        for (int i = 0; i < 4; ++i)
            af[i] = *reinterpret_cast<const short8*>(
                &a_lds[slot][(wm * 64 + i * 16 + l16) * BKP + rd]);
#pragma unroll
        for (int j = 0; j < 2; ++j)
            bf[j] = *reinterpret_cast<const short8*>(
                &b_lds[slot][(wn * 64 + j * 16 + l16) * BKP + rd]);
        dma16(Xs + kk,               &a_lds[ps][ldsA0]);
        dma16(Xs + 16 * DMODEL + kk, &a_lds[ps][ldsA1]);
        __builtin_amdgcn_s_barrier();
        asm volatile("s_waitcnt lgkmcnt(0)" ::: "memory");
        __builtin_amdgcn_sched_barrier(0);
        __builtin_amdgcn_s_setprio(1);
#pragma unroll
        for (int i = 0; i < 4; ++i)
#pragma unroll
            for (int j = 0; j < 2; ++j)
                acc[i][j] = __builtin_amdgcn_mfma_f32_16x16x32_bf16(af[i], bf[j], acc[i][j], 0, 0, 0);
        __builtin_amdgcn_s_setprio(0);
        __builtin_amdgcn_s_barrier();

        // -------- phase B: read bf[2..3] (reuse af), stage B(kt+2)
#pragma unroll
        for (int j = 0; j < 2; ++j)
            bf[j] = *reinterpret_cast<const short8*>(
                &b_lds[slot][(wn * 64 + (2 + j) * 16 + l16) * BKP + rd]);
        dma16(Ws + kk,               &b_lds[ps][ldsA0]);
        dma16(Ws + 16 * DMODEL + kk, &b_lds[ps][ldsA1]);
        __builtin_amdgcn_s_barrier();
        asm volatile("s_waitcnt lgkmcnt(0)" ::: "memory");
        __builtin_amdgcn_sched_barrier(0);
        __builtin_amdgcn_s_setprio(1);
#pragma unroll
        for (int i = 0; i < 4; ++i)
#pragma unroll
            for (int j = 0; j < 2; ++j)
                acc[i][2 + j] = __builtin_amdgcn_mfma_f32_16x16x32_bf16(af[i], bf[j], acc[i][2 + j], 0, 0, 0);
        __builtin_amdgcn_s_setprio(0);
        // boundary: in flight <= tiles kt+1 (4) + kt+2 (4); vmcnt(4) => kt+1 landed.
        asm volatile("s_waitcnt vmcnt(4)" ::: "memory");
        __builtin_amdgcn_s_barrier();
    }
    asm volatile("s_waitcnt vmcnt(0)" ::: "memory");   // retire wrapped dummy stages

    // ---- epilogue: bias (+ RoPE via table for Q/K); dense [bh][l][d] store
#pragma unroll
    for (int jf = 0; jf < 4; ++jf) {
        int nn = (bx & 7) * 128 + wn * 64 + jf * 16 + l16;   // 0..1023 within weight
        float bval = bias[nn];
        int d  = nn & (HEADD - 1);
        int h  = nn >> 6;
        float sgn = (d & 1) ? 1.0f : -1.0f;
        int i2 = d >> 1;
#pragma unroll
        for (int mf = 0; mf < 4; ++mf) {
#pragma unroll
            for (int r = 0; r < 4; ++r) {
                int m_g = m0 + wm * 64 + mf * 16 + quad * 4 + r;
                float v = acc[mf][jf][r] + bval;
                int b    = m_g >> 11;
                int lpos = m_g & (L_SEQ - 1);
                if (sel < 2) {
                    float p = __shfl_xor(v, 1);   // partner (d^1), same row
                    float2 cs = *reinterpret_cast<const float2*>(&rope[(size_t)(lpos * 32 + i2) * 2]);
                    v = v * cs.x + sgn * cs.y * p;
                    if (sel == 0) v *= 0.18033688011112042f;  // log2e/8
                }
                out[((size_t)(b * NHEAD + h) * L_SEQ + lpos) * HEADD + d] = f2bf(v);
            }
        }
    }
}

// ---------------- V transpose: [bh][l][d] -> [bh][d][l] ---------------------
__global__ __launch_bounds__(256) void transpose_v(
    const unsigned short* __restrict__ Vr, unsigned short* __restrict__ Vt)
{
    __shared__ unsigned short tile[64 * 72];
    const int tid = threadIdx.x;
    const int bh  = blockIdx.y;
    const int l0  = blockIdx.x * 64;
#pragma unroll
    for (int t = 0; t < 2; ++t) {
        int c = tid + t * 256;
        int row = c >> 3, cc = (c & 7) << 3;
        int4 v = *reinterpret_cast<const int4*>(Vr + ((size_t)bh * L_SEQ + l0 + row) * HEADD + cc);
        *reinterpret_cast<int4*>(&tile[row * 72 + cc]) = v;
    }
    __syncthreads();
#pragma unroll
    for (int t = 0; t < 2; ++t) {
        int c = tid + t * 256;
        int d = c >> 3, lc = (c & 7) << 3;
        union { unsigned short u[8]; int4 v; } tt;
#pragma unroll
        for (int j = 0; j < 8; ++j) tt.u[j] = tile[(lc + j) * 72 + d];
        *reinterpret_cast<int4*>(Vt + ((size_t)bh * HEADD + d) * L_SEQ + l0 + lc) = tt.v;
    }
}

// ---------------- flash attention (causal), S^T formulation -----------------
#define LDK 88

__global__ __launch_bounds__(256) void attn_fwd(
    const unsigned short* __restrict__ Q,
    const unsigned short* __restrict__ K,
    const unsigned short* __restrict__ Vt,
    unsigned short* __restrict__ Oa)
{
    __shared__ unsigned short k_lds[64 * LDK];
    __shared__ unsigned short v_lds[64 * LDK];
    const int tid  = threadIdx.x;
    const int lane = tid & 63;
    const int w    = tid >> 6;
    const int quad = lane >> 4, l16 = lane & 15;
    const int pair = blockIdx.x;
    const int bh   = blockIdx.y;
    const size_t base = (size_t)bh * L_SEQ * HEADD;

    const int srow0 = tid >> 3;
    const int scc   = (tid & 7) << 3;
    const int b = bh >> 4, h = bh & 15;

    for (int half = 0; half < 2; ++half) {
        const int qb = half ? (31 - pair) : pair;
        const int qrow = qb * 64 + w * 16 + l16;

        short8 qf[2];
#pragma unroll
        for (int ks = 0; ks < 2; ++ks)
            qf[ks] = *reinterpret_cast<const short8*>(Q + base + (size_t)qrow * HEADD + ks * 32 + quad * 8);

        f32x4 o[4];
#pragma unroll
        for (int nt = 0; nt < 4; ++nt) o[nt] = (f32x4){0.f, 0.f, 0.f, 0.f};
        float lsum = 0.f;

        int4 ka0 = *reinterpret_cast<const int4*>(K  + base + (size_t)srow0 * HEADD + scc);
        int4 ka1 = *reinterpret_cast<const int4*>(K  + base + (size_t)(srow0 + 32) * HEADD + scc);
        int4 va0 = *reinterpret_cast<const int4*>(Vt + base + (size_t)srow0 * L_SEQ + scc);
        int4 va1 = *reinterpret_cast<const int4*>(Vt + base + (size_t)(srow0 + 32) * L_SEQ + scc);

        for (int kb = 0; kb <= qb; ++kb) {
            __syncthreads();
            *reinterpret_cast<int4*>(&k_lds[srow0 * LDK + scc])        = ka0;
            *reinterpret_cast<int4*>(&k_lds[(srow0 + 32) * LDK + scc]) = ka1;
            *reinterpret_cast<int4*>(&v_lds[srow0 * LDK + scc])        = va0;
            *reinterpret_cast<int4*>(&v_lds[(srow0 + 32) * LDK + scc]) = va1;
            __syncthreads();

            if (kb < qb) {
                int kn = kb + 1;
                ka0 = *reinterpret_cast<const int4*>(K  + base + (size_t)(kn * 64 + srow0) * HEADD + scc);
                ka1 = *reinterpret_cast<const int4*>(K  + base + (size_t)(kn * 64 + srow0 + 32) * HEADD + scc);
                va0 = *reinterpret_cast<const int4*>(Vt + base + (size_t)srow0 * L_SEQ + kn * 64 + scc);
                va1 = *reinterpret_cast<const int4*>(Vt + base + (size_t)(srow0 + 32) * L_SEQ + kn * 64 + scc);
            }

            f32x4 st[4];
#pragma unroll
            for (int nt = 0; nt < 4; ++nt) st[nt] = (f32x4){0.f, 0.f, 0.f, 0.f};
#pragma unroll
            for (int ks = 0; ks < 2; ++ks)
#pragma unroll
                for (int nt = 0; nt < 4; ++nt) {
                    short8 kf = *reinterpret_cast<const short8*>(&k_lds[(nt * 16 + l16) * LDK + ks * 32 + quad * 8]);
                    st[nt] = __builtin_amdgcn_mfma_f32_16x16x32_bf16(kf, qf[ks], st[nt], 0, 0, 0);
                }

            if (kb == qb) {
#pragma unroll
                for (int nt = 0; nt < 4; ++nt)
#pragma unroll
                    for (int r = 0; r < 4; ++r) {
                        int seqcol = kb * 64 + nt * 16 + quad * 4 + r;
                        if (seqcol > qrow) st[nt][r] = -INFINITY;
                    }
            }

            short4v pfrag[4];
#pragma unroll
            for (int nt = 0; nt < 4; ++nt) {
                float p0 = __builtin_amdgcn_exp2f(st[nt][0]);
                float p1 = __builtin_amdgcn_exp2f(st[nt][1]);
                float p2 = __builtin_amdgcn_exp2f(st[nt][2]);
                float p3 = __builtin_amdgcn_exp2f(st[nt][3]);
                lsum += (p0 + p1) + (p2 + p3);
                unsigned u0 = __float_as_uint(p0) + 0x8000u;
                unsigned u1 = __float_as_uint(p1) + 0x8000u;
                unsigned u2 = __float_as_uint(p2) + 0x8000u;
                unsigned u3 = __float_as_uint(p3) + 0x8000u;
                union { unsigned u[2]; short4v v; } pk;
                pk.u[0] = (u0 >> 16) | (u1 & 0xffff0000u);
                pk.u[1] = (u2 >> 16) | (u3 & 0xffff0000u);
                pfrag[nt] = pk.v;
            }

#pragma unroll
            for (int c = 0; c < 4; ++c)
#pragma unroll
                for (int nt2 = 0; nt2 < 4; ++nt2) {
                    short4v vf = *reinterpret_cast<const short4v*>(
                        &v_lds[(nt2 * 16 + l16) * LDK + c * 16 + quad * 4]);
                    o[nt2] = __builtin_amdgcn_mfma_f32_16x16x16bf16_1k(pfrag[c], vf, o[nt2], 0, 0, 0);
                }
        }

        lsum += __shfl_xor(lsum, 16);
        lsum += __shfl_xor(lsum, 32);
        float rs[4];
#pragma unroll
        for (int r = 0; r < 4; ++r) rs[r] = __shfl(lsum, quad * 4 + r);
#pragma unroll
        for (int r = 0; r < 4; ++r) {
            float inv = 1.0f / rs[r];
            int lg = qb * 64 + w * 16 + quad * 4 + r;
#pragma unroll
            for (int nt = 0; nt < 4; ++nt) {
                int d = nt * 16 + l16;
                Oa[(size_t)(b * L_SEQ + lg) * DMODEL + h * HEADD + d] = f2bf(o[nt][r] * inv);
            }
        }
    }
}

// ---------------- output projection: fp32 out = A @ Wo^T + bo ---------------
__global__ __launch_bounds__(256) void out_gemm(
    const unsigned short* __restrict__ X,
    const unsigned short* __restrict__ W,
    const float* __restrict__ bias,
    float* __restrict__ out)
{
    __shared__ unsigned short a_lds[2][128 * LDA];
    __shared__ unsigned short b_lds[2][128 * LDA];
    const int tid  = threadIdx.x;
    const int lane = tid & 63;
    const int w    = tid >> 6;
    const int wm   = w & 1, wn = w >> 1;
    const int quad = lane >> 4, l16 = lane & 15;
    const int m0 = blockIdx.y * 128;
    const int n0 = blockIdx.x * 128;

    f32x4 acc[4][4];
#pragma unroll
    for (int i = 0; i < 4; ++i)
#pragma unroll
        for (int j = 0; j < 4; ++j) acc[i][j] = (f32x4){0.f, 0.f, 0.f, 0.f};

    const int drow = lane >> 2;
    const int dcol = (lane & 3) << 3;

#pragma unroll
    for (int t = 0; t < 2; ++t) {
        int r0 = w * 32 + t * 16;
        dma16(X + (size_t)(m0 + r0 + drow) * DMODEL + dcol, &a_lds[0][r0 * LDA]);
        dma16(W + (size_t)(n0 + r0 + drow) * DMODEL + dcol, &b_lds[0][r0 * LDA]);
    }

    for (int it = 0; it < 32; ++it) {
        __syncthreads();
        int cb = it & 1;
        if (it < 31) {
            int kk = (it + 1) * 32;
#pragma unroll
            for (int t = 0; t < 2; ++t) {
                int r0 = w * 32 + t * 16;
                dma16(X + (size_t)(m0 + r0 + drow) * DMODEL + kk + dcol, &a_lds[cb ^ 1][r0 * LDA]);
                dma16(W + (size_t)(n0 + r0 + drow) * DMODEL + kk + dcol, &b_lds[cb ^ 1][r0 * LDA]);
            }
        }
        short8 af[4], bf[4];
#pragma unroll
        for (int mt = 0; mt < 4; ++mt)
            af[mt] = *reinterpret_cast<const short8*>(&a_lds[cb][(wm * 64 + mt * 16 + l16) * LDA + quad * 8]);
#pragma unroll
        for (int nt = 0; nt < 4; ++nt)
            bf[nt] = *reinterpret_cast<const short8*>(&b_lds[cb][(wn * 64 + nt * 16 + l16) * LDA + quad * 8]);
#pragma unroll
        for (int mt = 0; mt < 4; ++mt)
#pragma unroll
            for (int nt = 0; nt < 4; ++nt)
                acc[mt][nt] = __builtin_amdgcn_mfma_f32_16x16x32_bf16(af[mt], bf[nt], acc[mt][nt], 0, 0, 0);
    }

#pragma unroll
    for (int nt = 0; nt < 4; ++nt) {
        int n_g = n0 + wn * 64 + nt * 16 + l16;
        float bv = bias[n_g];
#pragma unroll
        for (int mt = 0; mt < 4; ++mt)
#pragma unroll
            for (int r = 0; r < 4; ++r) {
                int m_g = m0 + wm * 64 + mt * 16 + quad * 4 + r;
                out[(size_t)m_g * DMODEL + n_g] = acc[mt][nt][r] + bv;
            }
    }
}

extern "C" void kernel_launch(void* const* d_in, const int* in_sizes, int n_in,
                              void* d_out, int out_size, void* d_ws, size_t ws_size,
                              hipStream_t stream) {
    const float* query = (const float*)d_in[0];
    const float* Wq = (const float*)d_in[1];
    const float* bq = (const float*)d_in[2];
    const float* Wk = (const float*)d_in[3];
    const float* bk = (const float*)d_in[4];
    const float* Wv = (const float*)d_in[5];
    const float* bv = (const float*)d_in[6];
    const float* Wo = (const float*)d_in[7];
    const float* bo = (const float*)d_in[8];
    float* out = (float*)d_out;

    unsigned short* ws  = (unsigned short*)d_ws;
    unsigned short* xb  = ws;                       // 8192*1024
    unsigned short* wqb = xb  + (size_t)8388608;    // 1024*1024 each, CONTIGUOUS wq|wk|wv|wo
    unsigned short* wkb = wqb + 1048576;
    unsigned short* wvb = wkb + 1048576;
    unsigned short* wob = wvb + 1048576;
    unsigned short* Qb  = wob + 1048576;            // [bh][l][d]
    unsigned short* Kb  = Qb  + 8388608;
    unsigned short* Vr  = Kb  + 8388608;            // [bh][l][d]
    unsigned short* Vtb = Vr  + 8388608;            // [bh][d][l]
    unsigned short* Ab  = Vtb + 8388608;            // [b][l][h*d]
    float* rope = (float*)(Ab + 8388608);           // 2048*32 float2 = 512 KB

    (void)wkb; (void)wvb;

    build_rope<<<256, 256, 0, stream>>>(rope);
    cvt_f32_bf16<<<8192, 256, 0, stream>>>(query, xb, 2097152);
    cvt_weights<<<4096, 256, 0, stream>>>(Wq, Wk, Wv, Wo, wqb);

    // fused QKV GEMM: M=8192 x N=3072, 128x128 tiles -> grid (24, 64) = 1536 blocks
    proj_qkv<<<dim3(24, 64), 256, 0, stream>>>(xb, wqb, bq, bk, bv, rope, Qb, Kb, Vr);
    transpose_v<<<dim3(32, 64), 256, 0, stream>>>(Vr, Vtb);
    attn_fwd<<<dim3(16, 64), 256, 0, stream>>>(Qb, Kb, Vtb, Ab);
    out_gemm<<<dim3(8, 64), 256, 0, stream>>>(Ab, wob, bo, out);
}